// Round 6
// baseline (680.414 us; speedup 1.0000x reference)
//
#include <hip/hip_runtime.h>
#include <cstdint>
#include <cstddef>

// Problem constants (from reference)
#define B_ 32
#define P_ 24576
#define C_ 80
#define O_ 32
#define TOPK_ 15

static __device__ __forceinline__ float iou1(float4 a, float4 b) {
    float tlx = fmaxf(a.x, b.x), tly = fmaxf(a.y, b.y);
    float brx = fminf(a.z, b.z), bry = fminf(a.w, b.w);
    float wx = fmaxf(brx - tlx, 0.f), wy = fmaxf(bry - tly, 0.f);
    float inter = wx * wy;
    float aa = (a.z - a.x) * (a.w - a.y);
    float ab = (b.z - b.x) * (b.w - b.y);
    return inter / (aa + ab - inter + 1e-9f);
}

// balanced_l1: alpha=0.5, gamma=1.5, beta=0.11, b=e^3-1 (constants compiler-folded)
static __device__ __forceinline__ float bl1(float pred, float target) {
    const float BB = 19.085536923187668f;  // e^3 - 1
    float d = fabsf(pred - target);
    float small = (0.5f / BB) * (BB * d + 1.f) * log1pf(BB * d / 0.11f) - 0.5f * d;
    float big = 1.5f * d + (1.5f / BB - 0.5f * 0.11f);
    return (d < 0.11f) ? small : big;
}

// ============ K1: compress masked q-matrices + focal t=0 partial ============
// Per (b,p): q1 column -> (colmax v1, rowmask m1); qr column -> (vr, mr).
// Ties preserved exactly via equality bits. Also accumulates sum of
// f(l,0) = sigmoid(l)^2 * softplus(l) over the 80-class conf row.
__global__ __launch_bounds__(256) void k1_compress(
        const float* __restrict__ loc, const float* __restrict__ conf,
        const float* __restrict__ priors, const float* __restrict__ targets,
        uint2* __restrict__ A1, uint2* __restrict__ Ar,
        double* __restrict__ f0_part) {
    const int bpb = P_ / 256;  // 96
    int b = blockIdx.x / bpb;
    int p = (blockIdx.x % bpb) * 256 + threadIdx.x;
    int tid = threadIdx.x;

    __shared__ float4 tbox[O_];
    __shared__ int tlab[O_];
    __shared__ int hitC[C_];
    __shared__ int slotC[C_];
    __shared__ int slotArr[O_];
    __shared__ float pcS[256 * 33];  // stride 33: bank-conflict-free
    __shared__ double red[256];

    if (tid < O_) {
        const float* t = targets + (b * O_ + tid) * 5;
        tbox[tid] = make_float4(t[0], t[1], t[2], t[3]);
        tlab[tid] = (int)t[4];
    }
    __syncthreads();
    if (tid < C_) {
        int hit = 0;
#pragma unroll
        for (int o = 0; o < O_; ++o) hit |= (tlab[o] == tid) ? 1 : 0;
        hitC[tid] = hit;
    }
    __syncthreads();
    if (tid < C_) {
        int s = 0;
        for (int c = 0; c < tid; ++c) s += hitC[c];
        slotC[tid] = hitC[tid] ? s : -1;
    }
    __syncthreads();
    if (tid < O_) slotArr[tid] = slotC[tlab[tid]];
    __syncthreads();

    // f(l,0) over the full row; stash sigmoids of needed classes in LDS
    const float* crow = conf + ((size_t)(b * P_ + p)) * C_;
    float f0 = 0.f;
    for (int cc = 0; cc < C_ / 4; ++cc) {
        float4 v4 = ((const float4*)crow)[cc];
        float vv[4] = {v4.x, v4.y, v4.z, v4.w};
#pragma unroll
        for (int j = 0; j < 4; ++j) {
            float l = vv[j];
            float e = expf(-fabsf(l));
            float sp = fmaxf(l, 0.f) + log1pf(e);                    // bce(l,0)
            float s = (l >= 0.f) ? 1.f / (1.f + e) : e / (1.f + e);  // sigmoid
            f0 += s * s * sp;
            int slot = slotC[cc * 4 + j];
            if (slot >= 0) pcS[tid * 33 + slot] = s;
        }
    }

    float4 pr = ((const float4*)priors)[p];
    float4 lc = ((const float4*)loc)[b * P_ + p];
    float4 pf = make_float4(pr.x - pr.z * 0.5f, pr.y - pr.w * 0.5f,
                            pr.x + pr.z * 0.5f, pr.y + pr.w * 0.5f);
    float cx = pr.x + lc.x * 0.1f * pr.z;
    float cy = pr.y + lc.y * 0.1f * pr.w;
    float w = pr.z * expf(lc.z * 0.2f);
    float h = pr.w * expf(lc.w * 0.2f);
    float4 dec = make_float4(cx - w * 0.5f, cy - h * 0.5f, cx + w * 0.5f, cy + h * 0.5f);

    float m1 = -1.f, mr = -1.f;
    unsigned mask1 = 0u, maskr = 0u;
#pragma unroll
    for (int o = 0; o < O_; ++o) {
        float4 t = tbox[o];
        float ov = iou1(t, pf);
        float q1 = iou1(t, dec);
        float pc = pcS[tid * 33 + slotArr[o]];
        float qr = powf(fmaxf(ov, 1e-12f), (2.f - pc) * 0.5f);
        if (q1 > m1) { m1 = q1; mask1 = 1u << o; }
        else if (q1 == m1) mask1 |= 1u << o;
        if (qr > mr) { mr = qr; maskr = 1u << o; }
        else if (qr == mr) maskr |= 1u << o;
    }
    size_t idx = (size_t)b * P_ + p;
    A1[idx] = make_uint2(__float_as_uint(m1), mask1);
    Ar[idx] = make_uint2(__float_as_uint(mr), maskr);

    red[tid] = (double)f0;
    __syncthreads();
    for (int s = 128; s > 0; s >>= 1) {
        if (tid < s) red[tid] += red[tid + s];
        __syncthreads();
    }
    if (tid == 0) f0_part[blockIdx.x] = red[0];
}

// ============ K2: per-row 15th-largest from compressed columns ============
// grid (64, 32): x = g = b*2 + mat (stride-64 linear ids ≡ 0 mod 8 -> all 32
// row-blocks of a group land on the same XCD's L2); y = o (truth row).
__global__ __launch_bounds__(256) void k2_topk(
        const uint2* __restrict__ A1, const uint2* __restrict__ Ar,
        float* __restrict__ thrAll) {
    int g = blockIdx.x;
    int b = g >> 1;
    const uint2* A = (g & 1) ? Ar : A1;
    int o = blockIdx.y;
    int tid = threadIdx.x;

    float a[TOPK_];
#pragma unroll
    for (int k = 0; k < TOPK_; ++k) a[k] = 0.f;
    const uint2* col = A + (size_t)b * P_;
    for (int j = tid; j < P_; j += 256) {
        uint2 e = col[j];
        if ((e.y >> o) & 1u) {
            float v = __uint_as_float(e.x);
            if (v > a[0]) {
                a[0] = v;
#pragma unroll
                for (int k = 0; k < TOPK_ - 1; ++k) {
                    if (a[k] > a[k + 1]) { float t = a[k]; a[k] = a[k + 1]; a[k + 1] = t; }
                }
            }
        }
    }
    __shared__ float cand[256 * TOPK_];
    __shared__ unsigned long long red[256];
#pragma unroll
    for (int k = 0; k < TOPK_; ++k) cand[tid * TOPK_ + k] = a[k];
    __syncthreads();

    float last = 0.f;
    for (int it = 0; it < TOPK_; ++it) {
        unsigned long long best = 0ull;
#pragma unroll
        for (int k = 0; k < TOPK_; ++k) {
            int slot = tid * TOPK_ + k;
            float v = cand[slot];
            if (v > 0.f) {
                unsigned long long key =
                    ((unsigned long long)__float_as_uint(v) << 32) |
                    (unsigned int)(0xFFFFFFFFu - (unsigned)slot);
                if (key > best) best = key;
            }
        }
        red[tid] = best;
        __syncthreads();
        for (int s = 128; s > 0; s >>= 1) {
            if (tid < s) {
                unsigned long long x = red[tid + s];
                if (x > red[tid]) red[tid] = x;
            }
            __syncthreads();
        }
        unsigned long long gk = red[0];
        last = (gk == 0ull) ? 0.f : __uint_as_float((unsigned)(gk >> 32));
        if (gk != 0ull && tid == 0) {
            int slot = (int)(0xFFFFFFFFu - (unsigned)(gk & 0xFFFFFFFFu));
            cand[slot] = -1.f;
        }
        __syncthreads();
    }
    if (tid == 0) thrAll[g * O_ + o] = last;
}

// ============ K3: assignments + balanced-L1 + focal correction ============
__global__ __launch_bounds__(256) void k3_assign(
        const float* __restrict__ loc, const float* __restrict__ conf,
        const float* __restrict__ priors, const float* __restrict__ targets,
        const uint2* __restrict__ A1, const uint2* __restrict__ Ar,
        const float* __restrict__ thrAll,
        double* __restrict__ l_part, double* __restrict__ c_part,
        int* __restrict__ pos_part, int* __restrict__ np_part) {
    const int bpb = P_ / 256;
    int b = blockIdx.x / bpb;
    int p = (blockIdx.x % bpb) * 256 + threadIdx.x;
    int tid = threadIdx.x;

    __shared__ float4 tbox[O_];
    __shared__ int tlab[O_];
    __shared__ float t1s[O_], trs[O_];
    __shared__ double sdl[256], sdc[256];
    __shared__ int s1[256], s2[256];
    if (tid < O_) {
        const float* t = targets + (b * O_ + tid) * 5;
        tbox[tid] = make_float4(t[0], t[1], t[2], t[3]);
        tlab[tid] = (int)t[4];
        t1s[tid] = thrAll[(b * 2 + 0) * O_ + tid];
        trs[tid] = thrAll[(b * 2 + 1) * O_ + tid];
    }
    __syncthreads();

    size_t idx = (size_t)b * P_ + p;
    uint2 e1 = A1[idx], er = Ar[idx];
    float v1 = __uint_as_float(e1.x), vr = __uint_as_float(er.x);

    // first (lowest-o) row in mask passing its threshold == jnp argmax semantics
    float bv = -1.f; int bo = 0;
    if (v1 > 0.f) {
        unsigned m = e1.y;
        while (m) {
            int o = __ffs(m) - 1;
            if (v1 >= t1s[o]) { bv = v1; bo = o; break; }
            m &= m - 1;
        }
    }
    float bvr = -1.f; int bor = 0;
    if (vr > 0.f) {
        unsigned m = er.y;
        while (m) {
            int o = __ffs(m) - 1;
            if (vr >= trs[o]) { bvr = vr; bor = o; break; }
            m &= m - 1;
        }
    }

    int npt = (bv >= 0.f) ? 1 : 0;
    double corr = 0.0;
    if (bv >= 0.f) {
        int lab = tlab[bo];
        float l = conf[idx * C_ + lab];
        float e = expf(-fabsf(l));
        float bce0 = fmaxf(l, 0.f) + log1pf(e);
        float s = (l >= 0.f) ? 1.f / (1.f + e) : e / (1.f + e);
        float t = bv;  // relu(overlap_t - 3)
        float d = t - s;
        corr = (double)(d * d * (bce0 - l * t)) - (double)(s * s * bce0);
    }

    double lsum = 0.0;
    int pos = 0;
    if (bvr >= 0.f) {
        pos = 1;
        float4 mt = tbox[bor];
        float4 pr = ((const float4*)priors)[p];
        float gx = ((mt.x + mt.z) * 0.5f - pr.x) / (0.1f * pr.z);
        float gy = ((mt.y + mt.w) * 0.5f - pr.y) / (0.1f * pr.w);
        float gw = logf(fmaxf((mt.z - mt.x) / pr.z, 1e-8f)) / 0.2f;
        float gh = logf(fmaxf((mt.w - mt.y) / pr.w, 1e-8f)) / 0.2f;
        const float* lrow = loc + idx * 4;
        lsum = (double)(bl1(lrow[0], gx) + bl1(lrow[1], gy) +
                        bl1(lrow[2], gw) + bl1(lrow[3], gh));
    }

    sdl[tid] = lsum; sdc[tid] = corr; s1[tid] = pos; s2[tid] = npt;
    __syncthreads();
    for (int s = 128; s > 0; s >>= 1) {
        if (tid < s) {
            sdl[tid] += sdl[tid + s];
            sdc[tid] += sdc[tid + s];
            s1[tid] += s1[tid + s];
            s2[tid] += s2[tid + s];
        }
        __syncthreads();
    }
    if (tid == 0) {
        l_part[blockIdx.x] = sdl[0];
        c_part[blockIdx.x] = sdc[0];
        pos_part[blockIdx.x] = s1[0];
        np_part[blockIdx.x] = s2[0];
    }
}

// ============ K5: final reduction ============
__global__ __launch_bounds__(256) void k5_final(
        const double* __restrict__ f0_part, const double* __restrict__ l_part,
        const double* __restrict__ c_part, const int* __restrict__ pos_part,
        const int* __restrict__ np_part, int n, float* __restrict__ out) {
    __shared__ double sda[256], sdb[256];
    __shared__ int sia[256], sib[256];
    double a = 0, c = 0;
    int cp = 0, cn = 0;
    for (int i = threadIdx.x; i < n; i += 256) {
        a += l_part[i];
        c += f0_part[i] + c_part[i];
        cp += pos_part[i];
        cn += np_part[i];
    }
    sda[threadIdx.x] = a; sdb[threadIdx.x] = c;
    sia[threadIdx.x] = cp; sib[threadIdx.x] = cn;
    __syncthreads();
    for (int s = 128; s > 0; s >>= 1) {
        if (threadIdx.x < s) {
            sda[threadIdx.x] += sda[threadIdx.x + s];
            sdb[threadIdx.x] += sdb[threadIdx.x + s];
            sia[threadIdx.x] += sia[threadIdx.x + s];
            sib[threadIdx.x] += sib[threadIdx.x + s];
        }
        __syncthreads();
    }
    if (threadIdx.x == 0) {
        int dp = sia[0] > 1 ? sia[0] : 1;
        int dn = sib[0] > 1 ? sib[0] : 1;
        out[0] = (float)(sda[0] / (double)dp);
        out[1] = (float)(sdb[0] / (double)dn);
    }
}

__global__ void k_ws_fail(float* out, float mb) {
    out[0] = mb;  // ws_size in MiB, surfaced through the validation report
    out[1] = -12345.f;
}

extern "C" void kernel_launch(void* const* d_in, const int* in_sizes, int n_in,
                              void* d_out, int out_size, void* d_ws, size_t ws_size,
                              hipStream_t stream) {
    const float* loc = (const float*)d_in[0];
    const float* conf = (const float*)d_in[1];
    const float* priors = (const float*)d_in[2];
    const float* targets = (const float*)d_in[3];
    float* out = (float*)d_out;
    char* ws = (char*)d_ws;

    size_t off = 0;
    auto alloc = [&](size_t bytes) {
        size_t o = off;
        off += (bytes + 255) & ~(size_t)255;
        return o;
    };
    const int NB = B_ * P_ / 256;  // 3072
    size_t o_A1 = alloc((size_t)B_ * P_ * 8);
    size_t o_Ar = alloc((size_t)B_ * P_ * 8);
    size_t o_th = alloc(2 * B_ * O_ * 4);
    size_t o_f0 = alloc(NB * 8);
    size_t o_lp = alloc(NB * 8);
    size_t o_cp = alloc(NB * 8);
    size_t o_pp = alloc(NB * 4);
    size_t o_np = alloc(NB * 4);

    if (ws_size < off) {
        k_ws_fail<<<1, 1, 0, stream>>>(out, (float)((double)ws_size / 1048576.0));
        return;
    }

    uint2* A1 = (uint2*)(ws + o_A1);
    uint2* Ar = (uint2*)(ws + o_Ar);
    float* thrAll = (float*)(ws + o_th);
    double* f0_part = (double*)(ws + o_f0);
    double* l_part = (double*)(ws + o_lp);
    double* c_part = (double*)(ws + o_cp);
    int* pos_part = (int*)(ws + o_pp);
    int* np_part = (int*)(ws + o_np);

    k1_compress<<<NB, 256, 0, stream>>>(loc, conf, priors, targets, A1, Ar, f0_part);
    k2_topk<<<dim3(2 * B_, O_), 256, 0, stream>>>(A1, Ar, thrAll);
    k3_assign<<<NB, 256, 0, stream>>>(loc, conf, priors, targets, A1, Ar, thrAll,
                                      l_part, c_part, pos_part, np_part);
    k5_final<<<1, 256, 0, stream>>>(f0_part, l_part, c_part, pos_part, np_part,
                                    NB, out);
}